// Round 27
// baseline (98.848 us; speedup 1.0000x reference)
//
#include <hip/hip_runtime.h>

#define NSAMP 4096
#define KCH   128
#define MDIM  7

typedef __attribute__((ext_vector_type(8))) short bf16x8;
typedef __attribute__((ext_vector_type(4))) float f32x4;
typedef __attribute__((ext_vector_type(4))) unsigned u32x4;

static constexpr int RB[4] = {0, 1, 4, 9};
static constexpr int RE[4] = {1, 4, 9, 16};
static constexpr int PR_L[16] = {0,1,1,1,2,2,2,2,2,3,3,3,3,3,3,3};
static constexpr int PR_M[16] = {0,0,1,2,0,1,2,3,4,0,1,2,3,4,5,6};

// path index by (L, l1, l2); -1 = no path  (Python enumeration order)
static constexpr int PIDX[4][4][4] = {
  { { 0,-1,-1,-1},{-1, 1,-1,-1},{-1,-1, 2,-1},{-1,-1,-1, 3} },
  { {-1, 4,-1,-1},{ 5, 6, 7,-1},{-1, 8, 9,10},{-1,-1,11,12} },
  { {-1,-1,13,-1},{-1,14,15,16},{17,18,19,20},{-1,21,22,23} },
  { {-1,-1,-1,24},{-1,-1,25,26},{-1,27,28,29},{30,31,32,33} }
};

// invalid (l,m) rows for zero-fill
static constexpr int ZL[12] = {0,0,0,0,0,0, 1,1,1,1, 2,2};
static constexpr int ZM[12] = {1,2,3,4,5,6, 3,4,5,6, 5,6};

#define WP_BYTES 1310720u   // 1280 sets * 512 shorts * 2B
#define BG_BYTES 16384u     // G matrix: 8 steps * 2(hi/lo) * 64 lanes * 8 bf16

static __device__ __forceinline__ unsigned short f2bf(float x) {
    unsigned u = __builtin_bit_cast(unsigned, x);
    u = u + 0x7FFFu + ((u >> 16) & 1u);
    return (unsigned short)(u >> 16);
}
static __device__ __forceinline__ float bf2f(unsigned short h) {
    unsigned u = ((unsigned)h) << 16;
    return __builtin_bit_cast(float, u);
}
static __device__ __forceinline__ float lo2f(unsigned w) {
    return __builtin_bit_cast(float, w << 16);
}
static __device__ __forceinline__ float hi2f(unsigned w) {
    return __builtin_bit_cast(float, w & 0xFFFF0000u);
}

// ---------------- K0: W -> bf16 hi/lo in B-fragment order ----------------
__global__ __launch_bounds__(256) void cg_prep(const float* __restrict__ mW,
                                               const float* __restrict__ iW,
                                               unsigned short* __restrict__ Wp)
{
    int gid = blockIdx.x * 256 + threadIdx.x;
    int lane = gid & 63;
    int set  = gid >> 6;                            // 1280 sets
    int spl = set & 1;
    int ks  = (set >> 1) & 3;
    int ct  = (set >> 3) & 7;
    int l   = (set >> 6) & 3;
    int mi  = set >> 8;                             // 0..4
    const float* src = (mi < 3) ? (mW + ((size_t)mi * 4 + l) * (KCH * KCH))
                                : (iW + ((size_t)(mi - 3) * 4 + l) * (KCH * KCH));
    int j  = ct * 16 + (lane & 15);
    int kb = ks * 32 + (lane >> 4) * 8;
    unsigned short o[8];
#pragma unroll
    for (int e = 0; e < 8; ++e) {
        float w = src[(size_t)(kb + e) * KCH + j];
        unsigned short h = f2bf(w);
        o[e] = spl ? f2bf(w - bf2f(h)) : h;
    }
    uint4 pk;
    unsigned* pw = (unsigned*)&pk;
#pragma unroll
    for (int q = 0; q < 4; ++q) pw[q] = (unsigned)o[2*q] | ((unsigned)o[2*q+1] << 16);
    *(uint4*)(Wp + (size_t)set * 512 + lane * 8) = pk;
}

// ---------------- K1: U -> G (pair-GEMM B operand) hi/lo in fragment order ----------------
__global__ __launch_bounds__(256) void cg_prepg(const float* __restrict__ U,
                                                unsigned short* __restrict__ Bg)
{
    const int gid  = blockIdx.x * 256 + threadIdx.x;   // 0..1023
    const int s    = gid >> 7;                         // k-step 0..7
    const int spl  = (gid >> 6) & 1;
    const int lane = gid & 63;
    const int c    = lane & 15;
    const int kb   = s * 32 + (lane >> 4) * 8;
    const int Lo   = PR_L[c], cm = PR_M[c];
    unsigned short o[8];
#pragma unroll
    for (int e = 0; e < 8; ++e) {
        const int k  = kb + e;
        const int i  = k >> 4, j = k & 15;
        const int l1 = PR_L[i], a = PR_M[i];
        const int l2 = PR_L[j], b = PR_M[j];
        const int p  = PIDX[Lo][l1][l2];
        float val = (p >= 0) ? U[p * 343 + (a * 7 + b) * 7 + cm] : 0.0f;
        unsigned short h = f2bf(val);
        o[e] = spl ? f2bf(val - bf2f(h)) : h;
    }
    uint4 pk;
    unsigned* pw = (unsigned*)&pk;
#pragma unroll
    for (int q = 0; q < 4; ++q) pw[q] = (unsigned)o[2*q] | ((unsigned)o[2*q+1] << 16);
    *(uint4*)(Bg + (size_t)((s * 2 + spl) * 64 + lane) * 8) = pk;
}

// A-fragment read from bf16 plane [256 rows][128], chunk-XOR swizzled by (key&7)
static __device__ __forceinline__ bf16x8 ldF(const unsigned short* P, int row16, int key, int c) {
    int cs = c ^ (key & 7);
    return *(const bf16x8*)(P + row16 * 128 + cs * 8);
}

// ---- stage feats -> single-bf16 LDS (rows r*16+sample, chunk-XOR by sample&7) ----
static __device__ __forceinline__ void stage_feats1(const float* __restrict__ feats,
                                                    unsigned short* Fh, int tid, int n0)
{
    const int row = tid >> 1;           // 0..255 = r*16 + nlr
    const int r   = row >> 4;
    const int nlr = row & 15;
    const int kh  = tid & 1;
    const int l = PR_L[r], m = PR_M[r];
    const float* g = feats + (((size_t)l * NSAMP + (n0 + nlr)) * MDIM + m) * KCH + kh * 64;
    unsigned short* fh = Fh + row * 128;
#pragma unroll
    for (int c8 = 0; c8 < 8; ++c8) {
        f32x4 a = *(const f32x4*)(g + c8 * 8);
        f32x4 b = *(const f32x4*)(g + c8 * 8 + 4);
        float v[8] = {a[0], a[1], a[2], a[3], b[0], b[1], b[2], b[3]};
        uint4 ph;
        unsigned* pw = (unsigned*)&ph;
#pragma unroll
        for (int q = 0; q < 4; ++q)
            pw[q] = (unsigned)f2bf(v[2*q]) | ((unsigned)f2bf(v[2*q+1]) << 16);
        const int cs = (kh * 8 + c8) ^ (nlr & 7);
        *(uint4*)(fh + cs * 8) = ph;
    }
}

// ---- one mixer sweep (2-MFMA: single-bf16 A, W hi/lo B) ----
static __device__ __forceinline__ void mix_sweep1(const unsigned short* Fh,
                                                  const bf16x8* __restrict__ Wp, int mi,
                                                  int ct, int lane, f32x4 (&acc)[16])
{
    const int kg = lane >> 4;
    const int l15 = lane & 15;
#pragma unroll
    for (int r = 0; r < 16; ++r) { acc[r][0]=acc[r][1]=acc[r][2]=acc[r][3]=0.0f; }
#pragma unroll
    for (int ks = 0; ks < 4; ++ks) {
#pragma unroll
        for (int l = 0; l < 4; ++l) {
            const int s0 = (((mi * 4 + l) * 8 + ct) * 4 + ks) * 2;
            bf16x8 bh = Wp[(size_t)s0 * 64 + lane];
            bf16x8 bl = Wp[(size_t)(s0 + 1) * 64 + lane];
#pragma unroll
            for (int r = RB[l]; r < RE[l]; ++r) {
                bf16x8 ah = ldF(Fh, r * 16 + l15, l15, ks * 4 + kg);
                acc[r] = __builtin_amdgcn_mfma_f32_16x16x32_bf16(ah, bh, acc[r], 0, 0, 0);
                acc[r] = __builtin_amdgcn_mfma_f32_16x16x32_bf16(ah, bl, acc[r], 0, 0, 0);
            }
        }
    }
}

// ---- dual mixer sweep: acc0 <- W[ma], acc1 <- W[mb]; A-fragments loaded ONCE ----
static __device__ __forceinline__ void mix_sweep2(const unsigned short* Fh,
                                                  const bf16x8* __restrict__ Wp, int ma, int mb,
                                                  int ct, int lane,
                                                  f32x4 (&acc0)[16], f32x4 (&acc1)[16])
{
    const int kg = lane >> 4;
    const int l15 = lane & 15;
#pragma unroll
    for (int r = 0; r < 16; ++r) {
        acc0[r][0]=acc0[r][1]=acc0[r][2]=acc0[r][3]=0.0f;
        acc1[r][0]=acc1[r][1]=acc1[r][2]=acc1[r][3]=0.0f;
    }
#pragma unroll
    for (int ks = 0; ks < 4; ++ks) {
#pragma unroll
        for (int l = 0; l < 4; ++l) {
            const int s0 = (((ma * 4 + l) * 8 + ct) * 4 + ks) * 2;
            const int s1 = (((mb * 4 + l) * 8 + ct) * 4 + ks) * 2;
            bf16x8 b0h = Wp[(size_t)s0 * 64 + lane];
            bf16x8 b0l = Wp[(size_t)(s0 + 1) * 64 + lane];
            bf16x8 b1h = Wp[(size_t)s1 * 64 + lane];
            bf16x8 b1l = Wp[(size_t)(s1 + 1) * 64 + lane];
#pragma unroll
            for (int r = RB[l]; r < RE[l]; ++r) {
                bf16x8 ah = ldF(Fh, r * 16 + l15, l15, ks * 4 + kg);
                acc0[r] = __builtin_amdgcn_mfma_f32_16x16x32_bf16(ah, b0h, acc0[r], 0, 0, 0);
                acc0[r] = __builtin_amdgcn_mfma_f32_16x16x32_bf16(ah, b0l, acc0[r], 0, 0, 0);
                acc1[r] = __builtin_amdgcn_mfma_f32_16x16x32_bf16(ah, b1h, acc1[r], 0, 0, 0);
                acc1[r] = __builtin_amdgcn_mfma_f32_16x16x32_bf16(ah, b1l, acc1[r], 0, 0, 0);
            }
        }
    }
}

// ---- TRANSPOSED plane: T[ch][smp*16+row] bf16, 128 ch x 256 = 64 KB.
// Chunk c = (smp*16+row)>>3 (32 per channel), physical p = (c&24)|((c&7)^(ch&7)).
// acc (C-layout: lane = channel col, elems = samples) -> transposed plane.
// Per lane: 8 vector b128 stores (vs 64 scalar). Bank-spread 2-way via XOR.
static __device__ __forceinline__ void acc_to_ldsT(const f32x4 (&acc)[16], unsigned short* T,
                                                   int ct, int lane)
{
    const int kg = lane >> 4;
    const int l15 = lane & 15;
    unsigned short* tb = T + (ct * 16 + l15) * 256;
    const int key = l15 & 7;
#pragma unroll
    for (int q = 0; q < 4; ++q) {
        const int smp = kg * 4 + q;
#pragma unroll
        for (int half = 0; half < 2; ++half) {
            const int c = smp * 2 + half;
            const int p = (c & 24) | ((c & 7) ^ key);
            u32x4 pk;
#pragma unroll
            for (int d = 0; d < 4; ++d) {
                unsigned w;
                asm("v_cvt_pk_bf16_f32 %0, %1, %2"
                    : "=v"(w) : "v"(acc[half * 8 + 2 * d][q]), "v"(acc[half * 8 + 2 * d + 1][q]));
                pk[d] = w;
            }
            *(u32x4*)(tb + p * 8) = pk;
        }
    }
}

// ---- TP over transposed planes: compute ALL 16 units into tpa (vector reads) ----
static __device__ __forceinline__ void tp_computeT(const unsigned short* CurT,
                                                   const unsigned short* MtT,
                                                   const bf16x8 (&bgh)[8], const bf16x8 (&bgl)[8],
                                                   int ct, int lane, f32x4 (&tpa)[16])
{
    const int kg  = lane >> 4;
    const int l15 = lane & 15;
    const int i0 = kg >> 1;
    const int j0h = (kg & 1);                 // mv chunk half (j0 = 8*j0h)
    const unsigned short* cb = CurT + (ct * 16 + l15) * 256;
    const unsigned short* mb = MtT  + (ct * 16 + l15) * 256;
    const int key = l15 & 7;
#pragma unroll
    for (int u = 0; u < 16; ++u) {
        const int c0 = u * 2, c1 = u * 2 + 1, cm = u * 2 + j0h;
        const int p0 = (c0 & 24) | ((c0 & 7) ^ key);
        const int p1 = (c1 & 24) | ((c1 & 7) ^ key);
        const int pm = (cm & 24) | ((cm & 7) ^ key);
        const u32x4 A0 = *(const u32x4*)(cb + p0 * 8);
        const u32x4 A1 = *(const u32x4*)(cb + p1 * 8);
        const u32x4 M0 = *(const u32x4*)(mb + pm * 8);
        float cvv[8], mvv[8];
#pragma unroll
        for (int s = 0; s < 4; ++s) {
            cvv[s]     = i0 ? hi2f(A0[s]) : lo2f(A0[s]);
            cvv[4 + s] = i0 ? hi2f(A1[s]) : lo2f(A1[s]);
        }
#pragma unroll
        for (int e = 0; e < 8; ++e) {
            mvv[e] = (e & 1) ? hi2f(M0[e >> 1]) : lo2f(M0[e >> 1]);
        }
        f32x4 acc = {0.0f, 0.0f, 0.0f, 0.0f};
#pragma unroll
        for (int s = 0; s < 8; ++s) {
            float pf[8];
#pragma unroll
            for (int e = 0; e < 8; ++e) pf[e] = cvv[s] * mvv[e];
            unsigned ah[4];
#pragma unroll
            for (int d = 0; d < 4; ++d) {
                asm("v_cvt_pk_bf16_f32 %0, %1, %2" : "=v"(ah[d]) : "v"(pf[2*d]), "v"(pf[2*d+1]));
            }
            const u32x4 AH = {ah[0], ah[1], ah[2], ah[3]};
            const bf16x8 a_h = __builtin_bit_cast(bf16x8, AH);
            acc = __builtin_amdgcn_mfma_f32_16x16x32_bf16(a_h, bgh[s], acc, 0, 0, 0);
            acc = __builtin_amdgcn_mfma_f32_16x16x32_bf16(a_h, bgl[s], acc, 0, 0, 0);
        }
        tpa[u] = acc;
    }
}

// ---- write all 16 tp units row-major [smp*16+crow][128] (key = (smp^crow)&7) ----
static __device__ __forceinline__ void tp_writeAll(unsigned short* P, int ct, int lane,
                                                   const f32x4 (&tpa)[16])
{
    const int kg  = lane >> 4;
    const int l15 = lane & 15;
    const int chA = ct * 2 + (kg >> 1);
    const int co4 = (kg * 4) & 7;
#pragma unroll
    for (int u = 0; u < 16; ++u) {
        const int cs = chA ^ ((u ^ l15) & 7);
        const int soff = (u * 16 + l15) * 128 + cs * 8 + co4;
        const unsigned short h0 = f2bf(tpa[u][0]);
        const unsigned short h1 = f2bf(tpa[u][1]);
        const unsigned short h2 = f2bf(tpa[u][2]);
        const unsigned short h3 = f2bf(tpa[u][3]);
        *(unsigned*)(P + soff)     = (unsigned)h0 | ((unsigned)h1 << 16);
        *(unsigned*)(P + soff + 2) = (unsigned)h2 | ((unsigned)h3 << 16);
    }
}

// ---- iter sweep: racc += mix(tp plane, W[miW]); rows smp*16+crow, key smp^crow ----
static __device__ __forceinline__ void iter_sweep(const unsigned short* Tp,
                                                  const bf16x8* __restrict__ Wp, int miW,
                                                  int ct, int lane, f32x4 (&racc)[16])
{
    const int kg = lane >> 4;
    const int l15 = lane & 15;
#pragma unroll
    for (int ks = 0; ks < 4; ++ks) {
#pragma unroll
        for (int l = 0; l < 4; ++l) {
            const int s0 = (((miW * 4 + l) * 8 + ct) * 4 + ks) * 2;
            bf16x8 bh = Wp[(size_t)s0 * 64 + lane];
            bf16x8 bl = Wp[(size_t)(s0 + 1) * 64 + lane];
#pragma unroll
            for (int r = RB[l]; r < RE[l]; ++r) {
                bf16x8 ah = ldF(Tp, l15 * 16 + r, l15 ^ r, ks * 4 + kg);
                racc[r] = __builtin_amdgcn_mfma_f32_16x16x32_bf16(ah, bh, racc[r], 0, 0, 0);
                racc[r] = __builtin_amdgcn_mfma_f32_16x16x32_bf16(ah, bl, racc[r], 0, 0, 0);
            }
        }
    }
}

// ---- full TP + iter block (transposed planes, single-barrier race-free) ----
static __device__ __forceinline__ void tp_iterT(unsigned short* CurT, const unsigned short* MtT,
                                                const bf16x8* __restrict__ Bg,
                                                const bf16x8* __restrict__ Wp, int miW,
                                                int ct, int lane, f32x4 (&racc)[16])
{
    bf16x8 bgh[8], bgl[8];
#pragma unroll
    for (int s = 0; s < 8; ++s) {
        bgh[s] = Bg[(size_t)(s * 2 + 0) * 64 + lane];
        bgl[s] = Bg[(size_t)(s * 2 + 1) * 64 + lane];
    }
    f32x4 tpa[16];
    tp_computeT(CurT, MtT, bgh, bgl, ct, lane, tpa);
    __syncthreads();                    // ALL transposed reads done (cur plane dead)
    tp_writeAll(CurT, ct, lane, tpa);   // overwrite with row-major tp
    __syncthreads();                    // tp complete before cross-wave iter reads
    iter_sweep(CurT, Wp, miW, ct, lane, racc);
}

// ---------------- fuseA: dual mix + TP + iter0 -> Pcur (bf16) ----------------
__global__ __launch_bounds__(512, 2) void cg_fuseA(const float* __restrict__ feats,
                                                   const bf16x8* __restrict__ Wp,
                                                   const bf16x8* __restrict__ Bg,
                                                   unsigned short* __restrict__ Pcur,
                                                   int base)
{
    extern __shared__ char smem[];
    unsigned short* Fh = (unsigned short*)smem;   // 64 KB feats -> curT -> tp plane
    unsigned short* Tp = Fh + 32768;              // 64 KB mtT plane

    const int tid  = threadIdx.x;
    const int lane = tid & 63;
    const int ct   = tid >> 6;
    const int nl0  = blockIdx.x * 16;
    const int kg   = lane >> 4;
    const int l15  = lane & 15;
    const int j    = ct * 16 + l15;

    stage_feats1(feats, Fh, tid, base + nl0);
    __syncthreads();                              // B1: feats staged

    f32x4 accC[16], accM[16];
    mix_sweep2(Fh, Wp, 0, 1, ct, lane, accC, accM);  // cur0 + mt1
    __syncthreads();                              // B2: feats reads done

    acc_to_ldsT(accC, Fh, ct, lane);              // cur0 -> transposed
    acc_to_ldsT(accM, Tp, ct, lane);              // mt1  -> transposed
    __syncthreads();                              // B3: planes complete
    tp_iterT(Fh, Tp, Bg, Wp, 3, ct, lane, accC);  // accC = cur1 = cur0 + mix(tp1, iW0)

#pragma unroll
    for (int r = 0; r < 16; ++r) {
#pragma unroll
        for (int q = 0; q < 4; ++q) {
            const int nl = nl0 + kg * 4 + q;
            Pcur[((size_t)nl * 16 + r) * KCH + j] = f2bf(accC[r][q]);
        }
    }
}

// ---------------- fuseB: mix2 + TP + iter1 -> out ----------------
__global__ __launch_bounds__(512, 2) void cg_fuseB(const float* __restrict__ feats,
                                                   const bf16x8* __restrict__ Wp,
                                                   const bf16x8* __restrict__ Bg,
                                                   const unsigned short* __restrict__ Pcur,
                                                   float* __restrict__ gout,
                                                   int base)
{
    extern __shared__ char smem[];
    unsigned short* Fh = (unsigned short*)smem;   // 64 KB feats -> curT -> tp plane
    unsigned short* Tp = Fh + 32768;              // 64 KB mtT plane

    const int tid  = threadIdx.x;
    const int lane = tid & 63;
    const int ct   = tid >> 6;
    const int nl0  = blockIdx.x * 16;
    const int kg   = lane >> 4;
    const int l15  = lane & 15;
    const int j    = ct * 16 + l15;

    // prefetch residual cur1 (bf16) — latency hides under staging + mix
    f32x4 racc[16];
#pragma unroll
    for (int r = 0; r < 16; ++r) {
#pragma unroll
        for (int q = 0; q < 4; ++q) {
            const int nl = nl0 + kg * 4 + q;
            racc[r][q] = bf2f(Pcur[((size_t)nl * 16 + r) * KCH + j]);
        }
    }

    stage_feats1(feats, Fh, tid, base + nl0);
    __syncthreads();                              // B1

    f32x4 accM[16];
    mix_sweep1(Fh, Wp, 2, ct, lane, accM);        // mt2
    __syncthreads();                              // B2: feats reads done

    acc_to_ldsT(racc, Fh, ct, lane);              // cur1 -> transposed
    acc_to_ldsT(accM, Tp, ct, lane);              // mt2  -> transposed
    __syncthreads();                              // B3: planes complete
    tp_iterT(Fh, Tp, Bg, Wp, 4, ct, lane, racc);  // racc = out = cur1 + mix(tp2, iW1)

#pragma unroll
    for (int r = 0; r < 16; ++r) {
#pragma unroll
        for (int q = 0; q < 4; ++q) {
            const int n = base + nl0 + kg * 4 + q;
            gout[(((size_t)PR_L[r] * NSAMP + n) * MDIM + PR_M[r]) * KCH + j] = racc[r][q];
        }
    }
    {
        const int j2 = tid & 127;
        const int g  = tid >> 7;     // 0..3
#pragma unroll
        for (int z = 0; z < 12; ++z) {
#pragma unroll
            for (int i = 0; i < 4; ++i) {
                const int n = base + nl0 + g * 4 + i;
                gout[(((size_t)ZL[z] * NSAMP + n) * MDIM + ZM[z]) * KCH + j2] = 0.0f;
            }
        }
    }
}

extern "C" void kernel_launch(void* const* d_in, const int* in_sizes, int n_in,
                              void* d_out, int out_size, void* d_ws, size_t ws_size,
                              hipStream_t stream)
{
    const float* feats = (const float*)d_in[0];
    const float* U     = (const float*)d_in[1];
    const float* mW    = (const float*)d_in[2];
    const float* iW    = (const float*)d_in[3];
    float* out = (float*)d_out;

    const size_t fixed = (size_t)WP_BYTES + BG_BYTES;
    size_t avail = (ws_size > fixed) ? (ws_size - fixed) : 0;
    int NC = (int)(avail / 4096);             // per-sample: Pcur bf16 = 16*128*2 B
    NC = (NC / 16) * 16;
    if (NC > NSAMP) NC = NSAMP;
    if (NC < 16) return;

    char* wsb = (char*)d_ws;
    unsigned short* Wp   = (unsigned short*)wsb;
    unsigned short* Bg   = (unsigned short*)(wsb + WP_BYTES);
    unsigned short* Pcur = (unsigned short*)(wsb + fixed);

    hipFuncSetAttribute(reinterpret_cast<const void*>(cg_fuseA),
                        hipFuncAttributeMaxDynamicSharedMemorySize, 131072);
    hipFuncSetAttribute(reinterpret_cast<const void*>(cg_fuseB),
                        hipFuncAttributeMaxDynamicSharedMemorySize, 131072);

    cg_prep<<<320, 256, 0, stream>>>(mW, iW, Wp);
    cg_prepg<<<4, 256, 0, stream>>>(U, Bg);

    for (int base = 0; base < NSAMP; base += NC) {
        const int nc = (NSAMP - base < NC) ? (NSAMP - base) : NC;
        cg_fuseA<<<nc / 16, 512, 131072, stream>>>(feats, (const bf16x8*)Wp,
                                                   (const bf16x8*)Bg, Pcur, base);
        cg_fuseB<<<nc / 16, 512, 131072, stream>>>(feats, (const bf16x8*)Wp,
                                                   (const bf16x8*)Bg, Pcur, out, base);
    }
}

// Round 28
// 94.742 us; speedup vs baseline: 1.0433x; 1.0433x over previous
//
#include <hip/hip_runtime.h>

#define NSAMP 4096
#define KCH   128
#define MDIM  7

typedef __attribute__((ext_vector_type(8))) short bf16x8;
typedef __attribute__((ext_vector_type(4))) float f32x4;
typedef __attribute__((ext_vector_type(4))) unsigned u32x4;

static constexpr int RB[4] = {0, 1, 4, 9};
static constexpr int RE[4] = {1, 4, 9, 16};
static constexpr int PR_L[16] = {0,1,1,1,2,2,2,2,2,3,3,3,3,3,3,3};
static constexpr int PR_M[16] = {0,0,1,2,0,1,2,3,4,0,1,2,3,4,5,6};

// path index by (L, l1, l2); -1 = no path  (Python enumeration order)
static constexpr int PIDX[4][4][4] = {
  { { 0,-1,-1,-1},{-1, 1,-1,-1},{-1,-1, 2,-1},{-1,-1,-1, 3} },
  { {-1, 4,-1,-1},{ 5, 6, 7,-1},{-1, 8, 9,10},{-1,-1,11,12} },
  { {-1,-1,13,-1},{-1,14,15,16},{17,18,19,20},{-1,21,22,23} },
  { {-1,-1,-1,24},{-1,-1,25,26},{-1,27,28,29},{30,31,32,33} }
};

// invalid (l,m) rows for zero-fill
static constexpr int ZL[12] = {0,0,0,0,0,0, 1,1,1,1, 2,2};
static constexpr int ZM[12] = {1,2,3,4,5,6, 3,4,5,6, 5,6};

#define WP_BYTES 1310720u   // 1280 sets * 512 shorts * 2B
#define BG_BYTES 16384u     // G matrix: 8 steps * 2(hi/lo) * 64 lanes * 8 bf16

static __device__ __forceinline__ unsigned short f2bf(float x) {
    unsigned u = __builtin_bit_cast(unsigned, x);
    u = u + 0x7FFFu + ((u >> 16) & 1u);
    return (unsigned short)(u >> 16);
}
static __device__ __forceinline__ float bf2f(unsigned short h) {
    unsigned u = ((unsigned)h) << 16;
    return __builtin_bit_cast(float, u);
}

// ---------------- K0: W -> bf16 hi/lo in B-fragment order ----------------
__global__ __launch_bounds__(256) void cg_prep(const float* __restrict__ mW,
                                               const float* __restrict__ iW,
                                               unsigned short* __restrict__ Wp)
{
    int gid = blockIdx.x * 256 + threadIdx.x;
    int lane = gid & 63;
    int set  = gid >> 6;                            // 1280 sets
    int spl = set & 1;
    int ks  = (set >> 1) & 3;
    int ct  = (set >> 3) & 7;
    int l   = (set >> 6) & 3;
    int mi  = set >> 8;                             // 0..4
    const float* src = (mi < 3) ? (mW + ((size_t)mi * 4 + l) * (KCH * KCH))
                                : (iW + ((size_t)(mi - 3) * 4 + l) * (KCH * KCH));
    int j  = ct * 16 + (lane & 15);
    int kb = ks * 32 + (lane >> 4) * 8;
    unsigned short o[8];
#pragma unroll
    for (int e = 0; e < 8; ++e) {
        float w = src[(size_t)(kb + e) * KCH + j];
        unsigned short h = f2bf(w);
        o[e] = spl ? f2bf(w - bf2f(h)) : h;
    }
    uint4 pk;
    unsigned* pw = (unsigned*)&pk;
#pragma unroll
    for (int q = 0; q < 4; ++q) pw[q] = (unsigned)o[2*q] | ((unsigned)o[2*q+1] << 16);
    *(uint4*)(Wp + (size_t)set * 512 + lane * 8) = pk;
}

// ---------------- K1: U -> G (pair-GEMM B operand) hi/lo in fragment order ----------------
__global__ __launch_bounds__(256) void cg_prepg(const float* __restrict__ U,
                                                unsigned short* __restrict__ Bg)
{
    const int gid  = blockIdx.x * 256 + threadIdx.x;   // 0..1023
    const int s    = gid >> 7;                         // k-step 0..7
    const int spl  = (gid >> 6) & 1;
    const int lane = gid & 63;
    const int c    = lane & 15;
    const int kb   = s * 32 + (lane >> 4) * 8;
    const int Lo   = PR_L[c], cm = PR_M[c];
    unsigned short o[8];
#pragma unroll
    for (int e = 0; e < 8; ++e) {
        const int k  = kb + e;
        const int i  = k >> 4, j = k & 15;
        const int l1 = PR_L[i], a = PR_M[i];
        const int l2 = PR_L[j], b = PR_M[j];
        const int p  = PIDX[Lo][l1][l2];
        float val = (p >= 0) ? U[p * 343 + (a * 7 + b) * 7 + cm] : 0.0f;
        unsigned short h = f2bf(val);
        o[e] = spl ? f2bf(val - bf2f(h)) : h;
    }
    uint4 pk;
    unsigned* pw = (unsigned*)&pk;
#pragma unroll
    for (int q = 0; q < 4; ++q) pw[q] = (unsigned)o[2*q] | ((unsigned)o[2*q+1] << 16);
    *(uint4*)(Bg + (size_t)((s * 2 + spl) * 64 + lane) * 8) = pk;
}

// A-fragment read from bf16 plane [256 rows][128], chunk-XOR swizzled by (key&7)
static __device__ __forceinline__ bf16x8 ldF(const unsigned short* P, int row16, int key, int c) {
    int cs = c ^ (key & 7);
    return *(const bf16x8*)(P + row16 * 128 + cs * 8);
}

// ---- stage feats -> single-bf16 LDS (rows r*16+sample, chunk-XOR by sample&7) ----
static __device__ __forceinline__ void stage_feats1(const float* __restrict__ feats,
                                                    unsigned short* Fh, int tid, int n0)
{
    const int row = tid >> 1;           // 0..255 = r*16 + nlr
    const int r   = row >> 4;
    const int nlr = row & 15;
    const int kh  = tid & 1;
    const int l = PR_L[r], m = PR_M[r];
    const float* g = feats + (((size_t)l * NSAMP + (n0 + nlr)) * MDIM + m) * KCH + kh * 64;
    unsigned short* fh = Fh + row * 128;
#pragma unroll
    for (int c8 = 0; c8 < 8; ++c8) {
        f32x4 a = *(const f32x4*)(g + c8 * 8);
        f32x4 b = *(const f32x4*)(g + c8 * 8 + 4);
        float v[8] = {a[0], a[1], a[2], a[3], b[0], b[1], b[2], b[3]};
        uint4 ph;
        unsigned* pw = (unsigned*)&ph;
#pragma unroll
        for (int q = 0; q < 4; ++q)
            pw[q] = (unsigned)f2bf(v[2*q]) | ((unsigned)f2bf(v[2*q+1]) << 16);
        const int cs = (kh * 8 + c8) ^ (nlr & 7);
        *(uint4*)(fh + cs * 8) = ph;
    }
}

// ---- one mixer sweep (2-MFMA: single-bf16 A, W hi/lo B) ----
static __device__ __forceinline__ void mix_sweep1(const unsigned short* Fh,
                                                  const bf16x8* __restrict__ Wp, int mi,
                                                  int ct, int lane, f32x4 (&acc)[16])
{
    const int kg = lane >> 4;
    const int l15 = lane & 15;
#pragma unroll
    for (int r = 0; r < 16; ++r) { acc[r][0]=acc[r][1]=acc[r][2]=acc[r][3]=0.0f; }
#pragma unroll
    for (int ks = 0; ks < 4; ++ks) {
#pragma unroll
        for (int l = 0; l < 4; ++l) {
            const int s0 = (((mi * 4 + l) * 8 + ct) * 4 + ks) * 2;
            bf16x8 bh = Wp[(size_t)s0 * 64 + lane];
            bf16x8 bl = Wp[(size_t)(s0 + 1) * 64 + lane];
#pragma unroll
            for (int r = RB[l]; r < RE[l]; ++r) {
                bf16x8 ah = ldF(Fh, r * 16 + l15, l15, ks * 4 + kg);
                acc[r] = __builtin_amdgcn_mfma_f32_16x16x32_bf16(ah, bh, acc[r], 0, 0, 0);
                acc[r] = __builtin_amdgcn_mfma_f32_16x16x32_bf16(ah, bl, acc[r], 0, 0, 0);
            }
        }
    }
}

// ---- write a C-layout accumulator into a bf16 LDS plane (rows sample*16+r, key=sample&7) ----
static __device__ __forceinline__ void acc_to_lds(const f32x4 (&acc)[16], unsigned short* P,
                                                  int ct, int lane)
{
    const int kg = lane >> 4;
    const int l15 = lane & 15;
    const int chnk = ct * 2 + (l15 >> 3);
#pragma unroll
    for (int r = 0; r < 16; ++r) {
#pragma unroll
        for (int q = 0; q < 4; ++q) {
            const int smp = kg * 4 + q;
            const int cs = chnk ^ (smp & 7);
            P[(smp * 16 + r) * 128 + cs * 8 + (l15 & 7)] = f2bf(acc[r][q]);
        }
    }
}

// ---- TP (pair-GEMM) + in-place tp overwrite + iter sweep ----
// Race-safety by SAMPLE-ROW groups (rows are swizzle-invariant): all waves
// finish reading group G's cur/mt rows (barrier) before anyone writes group
// G's tp rows. Group size 8 -> 3 internal barriers.
static __device__ __forceinline__ void tp_iter(unsigned short* Ch, const unsigned short* Mt,
                                               const bf16x8* __restrict__ Bg,
                                               const bf16x8* __restrict__ Wp, int miW,
                                               int ct, int lane, f32x4 (&racc)[16])
{
    const int kg  = lane >> 4;
    const int l15 = lane & 15;
    const int i0 = kg >> 1;
    const int j0 = (kg & 1) * 8;
    const int chnk = ct * 2 + (l15 >> 3);   // chunk of my load channel
    const int chA  = ct * 2 + (kg >> 1);    // chunk of my output channels ch0..ch0+3
    const int co4  = (kg * 4) & 7;

    bf16x8 bgh[8], bgl[8];
#pragma unroll
    for (int s = 0; s < 8; ++s) {
        bgh[s] = Bg[(size_t)(s * 2 + 0) * 64 + lane];
        bgl[s] = Bg[(size_t)(s * 2 + 1) * 64 + lane];
    }

    f32x4 tpa[8];
#pragma unroll 1
    for (int g = 0; g < 2; ++g) {
#pragma unroll
        for (int uu = 0; uu < 8; ++uu) {
            const int u = g * 8 + uu;
            const int cs = chnk ^ (u & 7);
            const unsigned short* cb = Ch + u * 2048 + cs * 8 + (l15 & 7);
            const unsigned short* mb = Mt + u * 2048 + cs * 8 + (l15 & 7);
            float cvv[8], mvv[8];
#pragma unroll
            for (int s = 0; s < 8; ++s) cvv[s] = bf2f(cb[(i0 + 2 * s) * 128]);
#pragma unroll
            for (int e = 0; e < 8; ++e) mvv[e] = bf2f(mb[(j0 + e) * 128]);
            f32x4 acc = {0.0f, 0.0f, 0.0f, 0.0f};
#pragma unroll
            for (int s = 0; s < 8; ++s) {
                float pf[8];
#pragma unroll
                for (int e = 0; e < 8; ++e) pf[e] = cvv[s] * mvv[e];
                unsigned ah[4];
#pragma unroll
                for (int d = 0; d < 4; ++d) {
                    asm("v_cvt_pk_bf16_f32 %0, %1, %2" : "=v"(ah[d]) : "v"(pf[2*d]), "v"(pf[2*d+1]));
                }
                const u32x4 AH = {ah[0], ah[1], ah[2], ah[3]};
                const bf16x8 a_h = __builtin_bit_cast(bf16x8, AH);
                acc = __builtin_amdgcn_mfma_f32_16x16x32_bf16(a_h, bgh[s], acc, 0, 0, 0);
                acc = __builtin_amdgcn_mfma_f32_16x16x32_bf16(a_h, bgl[s], acc, 0, 0, 0);
            }
            tpa[uu] = acc;
        }
        __syncthreads();   // ALL waves' reads of this 8-sample group done
#pragma unroll
        for (int uu = 0; uu < 8; ++uu) {
            const int u = g * 8 + uu;
            const int cs = chA ^ ((u ^ l15) & 7);          // bank-spread write key
            const int soff = (u * 16 + l15) * 128 + cs * 8 + co4;
            const unsigned short h0 = f2bf(tpa[uu][0]);
            const unsigned short h1 = f2bf(tpa[uu][1]);
            const unsigned short h2 = f2bf(tpa[uu][2]);
            const unsigned short h3 = f2bf(tpa[uu][3]);
            *(unsigned*)(Ch + soff)     = (unsigned)h0 | ((unsigned)h1 << 16);
            *(unsigned*)(Ch + soff + 2) = (unsigned)h2 | ((unsigned)h3 << 16);
        }
    }
    __syncthreads();   // all tp written before cross-wave iter reads

    // iter sweep: A = tp plane (rows sample*16 + crow, key = sample^crow)
#pragma unroll
    for (int ks = 0; ks < 4; ++ks) {
#pragma unroll
        for (int l = 0; l < 4; ++l) {
            const int s0 = (((miW * 4 + l) * 8 + ct) * 4 + ks) * 2;
            bf16x8 bh = Wp[(size_t)s0 * 64 + lane];
            bf16x8 bl = Wp[(size_t)(s0 + 1) * 64 + lane];
#pragma unroll
            for (int r = RB[l]; r < RE[l]; ++r) {
                bf16x8 ah = ldF(Ch, l15 * 16 + r, l15 ^ r, ks * 4 + kg);
                racc[r] = __builtin_amdgcn_mfma_f32_16x16x32_bf16(ah, bh, racc[r], 0, 0, 0);
                racc[r] = __builtin_amdgcn_mfma_f32_16x16x32_bf16(ah, bl, racc[r], 0, 0, 0);
            }
        }
    }
}

// ---------------- fuseA: mix0 + mix1 + TP + iter0 -> Pcur (bf16) ----------------
__global__ __launch_bounds__(512, 2) void cg_fuseA(const float* __restrict__ feats,
                                                   const bf16x8* __restrict__ Wp,
                                                   const bf16x8* __restrict__ Bg,
                                                   unsigned short* __restrict__ Pcur,
                                                   int base)
{
    extern __shared__ char smem[];
    unsigned short* Fh = (unsigned short*)smem;   // 64 KB feats -> cur/tp plane
    unsigned short* Tp = Fh + 32768;              // 64 KB mt plane

    const int tid  = threadIdx.x;
    const int lane = tid & 63;
    const int ct   = tid >> 6;
    const int nl0  = blockIdx.x * 16;
    const int kg   = lane >> 4;
    const int l15  = lane & 15;
    const int j    = ct * 16 + l15;

    stage_feats1(feats, Fh, tid, base + nl0);
    __syncthreads();                              // B1: feats staged

    f32x4 accC[16], accM[16];
    mix_sweep1(Fh, Wp, 0, ct, lane, accC);        // cur0
    mix_sweep1(Fh, Wp, 1, ct, lane, accM);        // mt1
    __syncthreads();                              // B2: feats reads done

    acc_to_lds(accC, Fh, ct, lane);               // cur0 bf16
    acc_to_lds(accM, Tp, ct, lane);               // mt1 bf16
    __syncthreads();                              // B3: planes complete
    tp_iter(Fh, Tp, Bg, Wp, 3, ct, lane, accC);   // accC = cur1 = cur0 + mix(tp1, iW0)

#pragma unroll
    for (int r = 0; r < 16; ++r) {
#pragma unroll
        for (int q = 0; q < 4; ++q) {
            const int nl = nl0 + kg * 4 + q;
            Pcur[((size_t)nl * 16 + r) * KCH + j] = f2bf(accC[r][q]);
        }
    }
}

// ---------------- fuseB: mix2 + TP + iter1 -> out ----------------
__global__ __launch_bounds__(512, 2) void cg_fuseB(const float* __restrict__ feats,
                                                   const bf16x8* __restrict__ Wp,
                                                   const bf16x8* __restrict__ Bg,
                                                   const unsigned short* __restrict__ Pcur,
                                                   float* __restrict__ gout,
                                                   int base)
{
    extern __shared__ char smem[];
    unsigned short* Fh = (unsigned short*)smem;   // 64 KB feats -> cur/tp plane
    unsigned short* Tp = Fh + 32768;              // 64 KB mt plane

    const int tid  = threadIdx.x;
    const int lane = tid & 63;
    const int ct   = tid >> 6;
    const int nl0  = blockIdx.x * 16;
    const int kg   = lane >> 4;
    const int l15  = lane & 15;
    const int j    = ct * 16 + l15;

    // prefetch residual cur1 (bf16) — latency hides under staging + mix
    f32x4 racc[16];
#pragma unroll
    for (int r = 0; r < 16; ++r) {
#pragma unroll
        for (int q = 0; q < 4; ++q) {
            const int nl = nl0 + kg * 4 + q;
            racc[r][q] = bf2f(Pcur[((size_t)nl * 16 + r) * KCH + j]);
        }
    }

    stage_feats1(feats, Fh, tid, base + nl0);
    __syncthreads();                              // B1

    f32x4 accM[16];
    mix_sweep1(Fh, Wp, 2, ct, lane, accM);        // mt2
    __syncthreads();                              // B2: feats reads done

    acc_to_lds(racc, Fh, ct, lane);               // cur1 bf16
    acc_to_lds(accM, Tp, ct, lane);               // mt2 bf16
    __syncthreads();                              // B3: planes complete
    tp_iter(Fh, Tp, Bg, Wp, 4, ct, lane, racc);   // racc = out = cur1 + mix(tp2, iW1)

#pragma unroll
    for (int r = 0; r < 16; ++r) {
#pragma unroll
        for (int q = 0; q < 4; ++q) {
            const int n = base + nl0 + kg * 4 + q;
            gout[(((size_t)PR_L[r] * NSAMP + n) * MDIM + PR_M[r]) * KCH + j] = racc[r][q];
        }
    }
    {
        const int j2 = tid & 127;
        const int g  = tid >> 7;     // 0..3
#pragma unroll
        for (int z = 0; z < 12; ++z) {
#pragma unroll
            for (int i = 0; i < 4; ++i) {
                const int n = base + nl0 + g * 4 + i;
                gout[(((size_t)ZL[z] * NSAMP + n) * MDIM + ZM[z]) * KCH + j2] = 0.0f;
            }
        }
    }
}

extern "C" void kernel_launch(void* const* d_in, const int* in_sizes, int n_in,
                              void* d_out, int out_size, void* d_ws, size_t ws_size,
                              hipStream_t stream)
{
    const float* feats = (const float*)d_in[0];
    const float* U     = (const float*)d_in[1];
    const float* mW    = (const float*)d_in[2];
    const float* iW    = (const float*)d_in[3];
    float* out = (float*)d_out;

    const size_t fixed = (size_t)WP_BYTES + BG_BYTES;
    size_t avail = (ws_size > fixed) ? (ws_size - fixed) : 0;
    int NC = (int)(avail / 4096);             // per-sample: Pcur bf16 = 16*128*2 B
    NC = (NC / 16) * 16;
    if (NC > NSAMP) NC = NSAMP;
    if (NC < 16) return;

    char* wsb = (char*)d_ws;
    unsigned short* Wp   = (unsigned short*)wsb;
    unsigned short* Bg   = (unsigned short*)(wsb + WP_BYTES);
    unsigned short* Pcur = (unsigned short*)(wsb + fixed);

    hipFuncSetAttribute(reinterpret_cast<const void*>(cg_fuseA),
                        hipFuncAttributeMaxDynamicSharedMemorySize, 131072);
    hipFuncSetAttribute(reinterpret_cast<const void*>(cg_fuseB),
                        hipFuncAttributeMaxDynamicSharedMemorySize, 131072);

    cg_prep<<<320, 256, 0, stream>>>(mW, iW, Wp);
    cg_prepg<<<4, 256, 0, stream>>>(U, Bg);

    for (int base = 0; base < NSAMP; base += NC) {
        const int nc = (NSAMP - base < NC) ? (NSAMP - base) : NC;
        cg_fuseA<<<nc / 16, 512, 131072, stream>>>(feats, (const bf16x8*)Wp,
                                                   (const bf16x8*)Bg, Pcur, base);
        cg_fuseB<<<nc / 16, 512, 131072, stream>>>(feats, (const bf16x8*)Wp,
                                                   (const bf16x8*)Bg, Pcur, out, base);
    }
}